// Round 7
// baseline (13015.179 us; speedup 1.0000x reference)
//
#include <hip/hip_runtime.h>

#define H 1024
#define V 32000
#define STEPS 375
#define NB1 256     // gru blocks
#define NB2 512     // logits blocks (2 per CU)

typedef float vfloat4 __attribute__((ext_vector_type(4)));

__device__ __forceinline__ float dot4(const float4 a, const float4 b) {
    return fmaf(a.x, b.x, fmaf(a.y, b.y, fmaf(a.z, b.z, a.w * b.w)));
}

__device__ __forceinline__ float wave_sum(float v) {
#pragma unroll
    for (int off = 32; off > 0; off >>= 1) v += __shfl_xor(v, off);
    return v;
}

__device__ __forceinline__ void sm_merge(float& m, float& ss, int& a,
                                         float om, float os, int oa) {
    if (om > m || (om == m && oa < a)) {
        ss = os + ss * expf(m - om); m = om; a = oa;
    } else {
        ss += os * expf(om - m);
    }
}

// load a 4-KB row's per-lane slice (16 B x 4), optionally nontemporal (no L3 alloc)
__device__ __forceinline__ void load_row4(const float4* p, int lane, float4 w[4], bool nt) {
    if (nt) {
        const vfloat4* q = (const vfloat4*)p;
#pragma unroll
        for (int j = 0; j < 4; ++j) {
            vfloat4 t = __builtin_nontemporal_load(&q[lane + 64 * j]);
            w[j] = make_float4(t.x, t.y, t.z, t.w);
        }
    } else {
#pragma unroll
        for (int j = 0; j < 4; ++j) w[j] = p[lane + 64 * j];
    }
}

// ---------------- init: h0 = enc ----------------
__global__ void init_kernel(const float* __restrict__ enc, float* __restrict__ h0) {
    for (int i = threadIdx.x; i < H; i += 256) h0[i] = enc[i];
}

// ---------------- per-step GRU (argmax feedback; logz[s-1] out) ----------------
__global__ __launch_bounds__(256) void gru_kernel(
    const float* __restrict__ emb, const float* __restrict__ W_ih,
    const float* __restrict__ W_hh, const float* __restrict__ b_ih,
    const float* __restrict__ b_hh, const float* __restrict__ h_cur,
    float* __restrict__ h_next, float* __restrict__ logz,
    const float* __restrict__ pm, const float* __restrict__ ps,
    const int* __restrict__ pa, int s) {
    const int tid = threadIdx.x;
    const int lane = tid & 63;
    const int wv = tid >> 6;
    const int b = blockIdx.x;

    int tok = 0;
    if (s > 0) {
        float m = -3.4e38f, ss = 0.f;
        int a = 0x7fffffff;
#pragma unroll
        for (int k = 0; k < NB2 / 64; ++k)
            sm_merge(m, ss, a, pm[k * 64 + lane], ps[k * 64 + lane], pa[k * 64 + lane]);
#pragma unroll
        for (int off = 32; off > 0; off >>= 1) {
            float om = __shfl_xor(m, off), os = __shfl_xor(ss, off);
            int oa = __shfl_xor(a, off);
            sm_merge(m, ss, a, om, os, oa);
        }
        tok = a;
        if (b == 0 && tid == 0) logz[s - 1] = m + logf(ss);
    }

    const int i = b * 4 + wv;   // GRU output row (4 waves, one row each)
    const float4* xp = (const float4*)(emb + (size_t)tok * H);
    const float4* hp = (const float4*)h_cur;
    float4 xv[4], hv[4];
#pragma unroll
    for (int j = 0; j < 4; ++j) {
        xv[j] = xp[lane + 64 * j];
        hv[j] = hp[lane + 64 * j];
    }
    float4 WX0[4], WX1[4], WX2[4], WH0[4], WH1[4], WH2[4];
    load_row4((const float4*)(W_ih + (size_t)i * H), lane, WX0, false);
    load_row4((const float4*)(W_ih + ((size_t)i + H) * H), lane, WX1, false);
    load_row4((const float4*)(W_ih + ((size_t)i + 2 * H) * H), lane, WX2, false);
    load_row4((const float4*)(W_hh + (size_t)i * H), lane, WH0, false);
    load_row4((const float4*)(W_hh + ((size_t)i + H) * H), lane, WH1, false);
    load_row4((const float4*)(W_hh + ((size_t)i + 2 * H) * H), lane, WH2, false);
    float sx0 = 0, sx1 = 0, sx2 = 0, sh0 = 0, sh1 = 0, sh2 = 0;
#pragma unroll
    for (int j = 0; j < 4; ++j) {
        sx0 += dot4(WX0[j], xv[j]); sx1 += dot4(WX1[j], xv[j]); sx2 += dot4(WX2[j], xv[j]);
        sh0 += dot4(WH0[j], hv[j]); sh1 += dot4(WH1[j], hv[j]); sh2 += dot4(WH2[j], hv[j]);
    }
    sx0 = wave_sum(sx0); sx1 = wave_sum(sx1); sx2 = wave_sum(sx2);
    sh0 = wave_sum(sh0); sh1 = wave_sum(sh1); sh2 = wave_sum(sh2);
    if (lane == 0) {
        const float rg = 1.f / (1.f + expf(-((sx0 + b_ih[i]) + (sh0 + b_hh[i]))));
        const float zg = 1.f / (1.f + expf(-((sx1 + b_ih[i + H]) + (sh1 + b_hh[i + H]))));
        const float ng = tanhf((sx2 + b_ih[i + 2 * H]) + rg * (sh2 + b_hh[i + 2 * H]));
        h_next[i] = (1.f - zg) * ng + zg * h_cur[i];
    }
}

// ---------------- per-step logits GEMV + online-softmax partials ----------------
// waves 3 and 7 use nontemporal weight loads (25% of lin_W never allocates in L3,
// keeping the L3-resident cyclic set ~123 MB < 256 MB to avoid LRU thrash)
__global__ __launch_bounds__(512, 4) void logits_kernel(
    const float* __restrict__ lin_W, const float* __restrict__ lin_b,
    const float* __restrict__ h_src, float* __restrict__ orow,
    float* __restrict__ pm, float* __restrict__ ps, int* __restrict__ pa) {
    const int tid = threadIdx.x;
    const int lane = tid & 63;
    const int wv = tid >> 6;
    const int b = blockIdx.x;
    const int row0 = (b < 256) ? 63 * b : 16128 + 62 * (b - 256);
    const int nrows = (b < 256) ? 63 : 62;
    const bool nt = (wv == 3) || (wv == 7);

    __shared__ float red_m[8], red_s[8];
    __shared__ int red_a[8];

    const float4* h4 = (const float4*)h_src;
    float4 hr[4];
#pragma unroll
    for (int j = 0; j < 4; ++j) hr[j] = h4[lane + 64 * j];

    float m = -3.4e38f, ssum = 0.f;
    int arg = 0x7fffffff;
    for (int r = wv; r < nrows; r += 32) {
        const int rB = r + 8, rC = r + 16, rD = r + 24;
        const bool vB = rB < nrows, vC = rC < nrows, vD = rD < nrows;
        float4 wA[4], wB[4], wC[4], wD[4];
        load_row4((const float4*)(lin_W + (size_t)(row0 + r) * H), lane, wA, nt);
        load_row4((const float4*)(lin_W + (size_t)(row0 + (vB ? rB : r)) * H), lane, wB, nt);
        load_row4((const float4*)(lin_W + (size_t)(row0 + (vC ? rC : r)) * H), lane, wC, nt);
        load_row4((const float4*)(lin_W + (size_t)(row0 + (vD ? rD : r)) * H), lane, wD, nt);
        __builtin_amdgcn_sched_barrier(0);
        float aA = 0, aB = 0, aC = 0, aD = 0;
#pragma unroll
        for (int j = 0; j < 4; ++j) {
            aA += dot4(wA[j], hr[j]); aB += dot4(wB[j], hr[j]);
            aC += dot4(wC[j], hr[j]); aD += dot4(wD[j], hr[j]);
        }
        aA = wave_sum(aA); aB = wave_sum(aB);
        aC = wave_sum(aC); aD = wave_sum(aD);
        aA += lin_b[row0 + r];
        if (lane == 0) __builtin_nontemporal_store(aA, &orow[row0 + r]);
        if (aA > m) { ssum *= expf(m - aA); m = aA; arg = row0 + r; }
        ssum += expf(aA - m);
        if (vB) {
            aB += lin_b[row0 + rB];
            if (lane == 0) __builtin_nontemporal_store(aB, &orow[row0 + rB]);
            if (aB > m) { ssum *= expf(m - aB); m = aB; arg = row0 + rB; }
            ssum += expf(aB - m);
        }
        if (vC) {
            aC += lin_b[row0 + rC];
            if (lane == 0) __builtin_nontemporal_store(aC, &orow[row0 + rC]);
            if (aC > m) { ssum *= expf(m - aC); m = aC; arg = row0 + rC; }
            ssum += expf(aC - m);
        }
        if (vD) {
            aD += lin_b[row0 + rD];
            if (lane == 0) __builtin_nontemporal_store(aD, &orow[row0 + rD]);
            if (aD > m) { ssum *= expf(m - aD); m = aD; arg = row0 + rD; }
            ssum += expf(aD - m);
        }
    }
    if (lane == 0) { red_m[wv] = m; red_s[wv] = ssum; red_a[wv] = arg; }
    __syncthreads();
    if (tid == 0) {
        float M = red_m[0], S = red_s[0];
        int A = red_a[0];
#pragma unroll
        for (int w = 1; w < 8; ++w) sm_merge(M, S, A, red_m[w], red_s[w], red_a[w]);
        pm[b] = M; ps[b] = S; pa[b] = A;
    }
}

// ---------------- final: out[s] -= logz[s] for s in 0..STEPS-2 ----------------
__global__ __launch_bounds__(256) void final_kernel(float* __restrict__ out,
                                                    const float* __restrict__ logz) {
    const int row = blockIdx.x >> 3;        // 0..373
    const int seg = blockIdx.x & 7;         // 8 segments of 1000 float4
    const float lz = logz[row];
    float4* p = (float4*)(out + (size_t)row * V) + seg * 1000;
    for (int i = threadIdx.x; i < 1000; i += 256) {
        float4 v = p[i];
        v.x -= lz; v.y -= lz; v.z -= lz; v.w -= lz;
        p[i] = v;
    }
}

// ---------------- tail: finalize out[STEPS-1] + write h_final ----------------
__global__ __launch_bounds__(256) void tail_kernel(
    float* __restrict__ out_last, const float* __restrict__ pm,
    const float* __restrict__ ps, const int* __restrict__ pa,
    const float* __restrict__ h_final, float* __restrict__ out_h) {
    const int tid = threadIdx.x;
    const int lane = tid & 63;
    const int b = blockIdx.x;
    float m = -3.4e38f, ss = 0.f;
    int a = 0x7fffffff;
#pragma unroll
    for (int k = 0; k < NB2 / 64; ++k)
        sm_merge(m, ss, a, pm[k * 64 + lane], ps[k * 64 + lane], pa[k * 64 + lane]);
#pragma unroll
    for (int off = 32; off > 0; off >>= 1) {
        float om = __shfl_xor(m, off), os = __shfl_xor(ss, off);
        int oa = __shfl_xor(a, off);
        sm_merge(m, ss, a, om, os, oa);
    }
    const float logZ = m + logf(ss);
    if (tid < 125) out_last[b * 125 + tid] -= logZ;
    if (b == 0)
        for (int i = tid; i < H; i += 256) out_h[i] = h_final[i];
}

extern "C" void kernel_launch(void* const* d_in, const int* in_sizes, int n_in,
                              void* d_out, int out_size, void* d_ws, size_t ws_size,
                              hipStream_t stream) {
    const float* enc = (const float*)d_in[0];
    const float* emb = (const float*)d_in[1];
    const float* W_ih = (const float*)d_in[2];
    const float* W_hh = (const float*)d_in[3];
    const float* b_ih = (const float*)d_in[4];
    const float* b_hh = (const float*)d_in[5];
    const float* lin_W = (const float*)d_in[6];
    const float* lin_b = (const float*)d_in[7];
    float* out = (float*)d_out;
    float* ws = (float*)d_ws;

    // ws: h_buf[2][H] | pm[NB2] | ps[NB2] | pa[NB2](int) | logz[STEPS]
    float* h_buf = ws;
    float* pm = ws + 2 * H;
    float* ps = pm + NB2;
    int* pa = (int*)(ps + NB2);
    float* logz = (float*)(pa + NB2);

    init_kernel<<<1, 256, 0, stream>>>(enc, h_buf);
    for (int s = 0; s < STEPS; ++s) {
        float* h_cur = h_buf + (s & 1) * H;
        float* h_next = h_buf + ((s + 1) & 1) * H;
        gru_kernel<<<NB1, 256, 0, stream>>>(emb, W_ih, W_hh, b_ih, b_hh,
                                            h_cur, h_next, logz, pm, ps, pa, s);
        logits_kernel<<<NB2, 512, 0, stream>>>(lin_W, lin_b, h_next,
                                               out + (size_t)s * V, pm, ps, pa);
    }
    final_kernel<<<(STEPS - 1) * 8, 256, 0, stream>>>(out, logz);
    tail_kernel<<<NB1, 256, 0, stream>>>(out + (size_t)(STEPS - 1) * V, pm, ps, pa,
                                         h_buf + (STEPS & 1) * H,
                                         out + (size_t)V * STEPS);
}